// Round 13
// baseline (952.697 us; speedup 1.0000x reference)
//
#include <hip/hip_runtime.h>
#include <cmath>

#define L_SEQ 2048
#define DM 512
#define DI 1024      // D_INNER
#define DS 16        // D_STATE
#define NSP 1056     // DI + 2*DS
#define NC 64        // scan chunks
#define CL 32        // chunk length

typedef unsigned short ushortT;
typedef unsigned int u32;
typedef __attribute__((ext_vector_type(8))) short short8;
typedef __attribute__((ext_vector_type(4))) unsigned short ushort4_t;
typedef __attribute__((ext_vector_type(4))) float float4_t;
typedef __attribute__((address_space(1))) u32 gu32;
typedef __attribute__((address_space(3))) u32 lu32;

__device__ __forceinline__ float sigm(float x) { return 1.0f / (1.0f + __expf(-x)); }

__device__ __forceinline__ ushortT f2bf(float f) {
    unsigned u = __float_as_uint(f);
    unsigned r = u + 0x7FFFu + ((u >> 16) & 1u);
    return (ushortT)(r >> 16);
}
__device__ __forceinline__ float b2f(ushortT u) {
    return __uint_as_float(((u32)u) << 16);
}
__device__ __forceinline__ void gl2lds16(const ushortT* g, ushortT* l) {
    __builtin_amdgcn_global_load_lds((gu32*)g, (lu32*)l, 16, 0, 0);
}

struct WC {
    const float* src[11];
    ushortT* dst[11];
    int ss[11], soff[11], ds_[11], tN[11], mode[11];
    int off[12];
};

struct KP {
    WC wc; int nW, nprep;
    const float* x; ushortT* XB;
    const float *xpb0, *xpb1, *dtW0, *dtW1, *dtb0, *dtb1;
    const float *outb0, *outb1, *fuW, *fub;
    float *BFdt0, *BFdt1, *BFof;
    const float *inb0, *inb1;
    ushortT *WtIn, *WtDt, *WtFu, *WtXpF, *XpD, *OutC, *WtOF2;
    ushortT *XSb, *Zb, *SCb, *DTbB, *Gb;
    float *BCf;
    const float *cw0, *cw1, *cb0, *cb1;
    const float *Alog, *Dp;
    float *Pend, *Hl;
    int* flags;
    float* out;
};

// ---- MFMA GEMM tile (BK=64, double-buffered LDS, XOR bank swizzle) ----
template<int BM, int BN>
__device__ void gemm_core(
    ushortT* As, ushortT* Bs, int bm, int bn,
    const ushortT* __restrict__ A, int lda, int revA,
    const ushortT* __restrict__ A2, int dualK,
    const ushortT* __restrict__ W,
    const float* __restrict__ bias,
    float* __restrict__ Cf, int ldcf,
    float* __restrict__ Cf2, int ldcf2, int Nsplit,
    ushortT* __restrict__ Cb, int ldcb,
    ushortT* __restrict__ Cb2, int ldcb2,
    int M, int N, int K, int epi)
{
    constexpr int BK = 64;
    constexpr int MI = BM / 32;
    constexpr int NI = BN / 32;
    constexpr int CA = BM / 32;
    constexpr int CB = BN / 32;
    constexpr int ABUF = BM * BK;
    constexpr int BBUF = BN * BK;

    const int tid  = threadIdx.x;
    const int wave = tid >> 6;
    const int lane = tid & 63;
    const int quad = lane >> 4;
    const int r    = lane & 15;
    const int wm   = (wave >> 1) * (BM / 2);
    const int wn   = (wave & 1) * (BN / 2);

    const int lrow = lane >> 3;
    const int lk   = ((lane & 7) ^ lrow) * 8;

    const ushortT* gA[CA]; const ushortT* gA2[CA]; ushortT* lA[CA];
    #pragma unroll
    for (int c = 0; c < CA; ++c) {
        int row = bm + c * 32 + wave * 8 + lrow;
        int r0 = revA ? (M - 1 - row) : row;
        gA[c] = A + (size_t)r0 * lda + lk;
        gA2[c] = dualK ? (A2 + (size_t)(M - 1 - row) * lda + lk) : gA[c];
        lA[c] = &As[(c * 32 + wave * 8) * BK];
    }
    const ushortT* gB[CB]; ushortT* lB[CB];
    #pragma unroll
    for (int c = 0; c < CB; ++c) {
        int row = bn + c * 32 + wave * 8 + lrow;
        if (row > N - 1) row = N - 1;
        gB[c] = W + (size_t)row * K + lk;
        lB[c] = &Bs[(c * 32 + wave * 8) * BK];
    }

    float4_t acc[MI][NI];
    #pragma unroll
    for (int i = 0; i < MI; ++i)
        #pragma unroll
        for (int j = 0; j < NI; ++j)
            acc[i][j] = (float4_t){0.f, 0.f, 0.f, 0.f};

    const int nsteps = K >> 6;

    auto stage = [&](int step, int buf) {
        int kq = step << 6;
        #pragma unroll
        for (int c = 0; c < CA; ++c) {
            const ushortT* s = (!dualK || kq < 1024) ? gA[c] + kq : gA2[c] + (kq - 1024);
            gl2lds16(s, lA[c] + buf * ABUF);
        }
        #pragma unroll
        for (int c = 0; c < CB; ++c)
            gl2lds16(gB[c] + kq, lB[c] + buf * BBUF);
    };
    auto compute = [&](int buf) {
        #pragma unroll
        for (int kh = 0; kh < 2; ++kh) {
            const int slot = (((kh * 4 + quad) ^ (lane & 7)) * 8);
            short8 af[MI], bf[NI];
            #pragma unroll
            for (int mi = 0; mi < MI; ++mi)
                af[mi] = *(const short8*)&As[buf * ABUF + (wm + mi * 16 + r) * BK + slot];
            #pragma unroll
            for (int ni = 0; ni < NI; ++ni)
                bf[ni] = *(const short8*)&Bs[buf * BBUF + (wn + ni * 16 + r) * BK + slot];
            #pragma unroll
            for (int mi = 0; mi < MI; ++mi)
                #pragma unroll
                for (int ni = 0; ni < NI; ++ni)
                    acc[mi][ni] = __builtin_amdgcn_mfma_f32_16x16x32_bf16(
                        af[mi], bf[ni], acc[mi][ni], 0, 0, 0);
        }
    };

    stage(0, 0);
    for (int i = 0; i < nsteps; i += 2) {
        __syncthreads();
        if (i + 1 < nsteps) stage(i + 1, 1);
        compute(0);
        __syncthreads();
        if (i + 2 < nsteps) stage(i + 2, 0);
        compute(1);
    }

    // epilogue: C/D layout col = lane&15, row = quad*4 + reg
    #pragma unroll
    for (int mi = 0; mi < MI; ++mi) {
        int rowb = bm + wm + mi * 16 + quad * 4;
        #pragma unroll
        for (int ni = 0; ni < NI; ++ni) {
            int gn = bn + wn + ni * 16 + r;
            if (gn < N) {
                float bv = bias ? bias[gn] : 0.0f;
                #pragma unroll
                for (int j = 0; j < 4; ++j) {
                    int orow = rowb + j;
                    float v = acc[mi][ni][j] + bv;
                    if (gn < Nsplit) {
                        if (epi == 1) v = (v > 20.0f) ? v : log1pf(__expf(v));
                        if (Cf) Cf[(size_t)orow * ldcf + gn] = v;
                        if (Cb) Cb[(size_t)orow * ldcb + gn] = f2bf(v);
                    } else {
                        if (Cf2) Cf2[(size_t)orow * ldcf2 + gn - Nsplit] = v;
                        if (Cb2) Cb2[(size_t)orow * ldcb2 + gn - Nsplit] = f2bf(v);
                    }
                }
            }
        }
    }
}

// ---- prep kernel: weight cvt / x cvt / bias folds ----
__global__ __launch_bounds__(256) void prep_k(KP p)
{
    __shared__ ushortT smem[2624];
    ushortT (*t)[33] = (ushortT(*)[33])smem;
    float* red = (float*)(smem + 2112);
    int b = blockIdx.x;
    int tid = threadIdx.x;
    if (b < p.nW) {
        const WC& wc = p.wc;
        int m = 0;
        while (b >= wc.off[m + 1]) ++m;
        int tl = b - wc.off[m];
        int n0 = (tl % wc.tN[m]) * 32;
        int k0 = (tl / wc.tN[m]) * 32;
        const float* W = wc.src[m];
        ushortT* D = wc.dst[m];
        int ss = wc.ss[m], soff = wc.soff[m], ds = wc.ds_[m];
        int tx = tid & 31, ty = tid >> 5;
        if (wc.mode[m] == 1) {
            #pragma unroll
            for (int i = 0; i < 32; i += 8)
                D[(size_t)(k0 + ty + i) * ds + n0 + tx] =
                    f2bf(W[(size_t)(k0 + ty + i) * ss + soff + n0 + tx]);
        } else {
            #pragma unroll
            for (int i = 0; i < 32; i += 8)
                t[ty + i][tx] = f2bf(W[(size_t)(k0 + ty + i) * ss + soff + n0 + tx]);
            __syncthreads();
            #pragma unroll
            for (int i = 0; i < 32; i += 8)
                D[(size_t)(n0 + ty + i) * ds + k0 + tx] = t[tx][ty + i];
        }
        return;
    }
    b -= p.nW;
    if (b < 1024) {
        int i = (b * 256 + tid) * 4;
        float4_t v = *(const float4_t*)(p.x + i);
        p.XB[i + 0] = f2bf(v[0]); p.XB[i + 1] = f2bf(v[1]);
        p.XB[i + 2] = f2bf(v[2]); p.XB[i + 3] = f2bf(v[3]);
        return;
    }
    int o = b - 1024;
    float acc = 0.0f;
    if (o < 2112) {
        int dir = o >= 1056;
        int m = o - dir * 1056;
        const float* xpb = dir ? p.xpb1 : p.xpb0;
        float* BF = dir ? p.BFdt1 : p.BFdt0;
        if (m >= 1024) {
            if (tid == 0) BF[m] = xpb[m];
            return;
        }
        const float* dtW = dir ? p.dtW1 : p.dtW0;
        const float* dtb = dir ? p.dtb1 : p.dtb0;
        for (int n = tid; n < 1024; n += 256) acc += xpb[n] * dtW[n * 1024 + m];
        red[tid] = acc;
        __syncthreads();
        for (int s = 128; s > 0; s >>= 1) {
            if (tid < s) red[tid] += red[tid + s];
            __syncthreads();
        }
        if (tid == 0) BF[m] = red[0] + dtb[m];
    } else {
        int n = o - 2112;
        for (int j = tid; j < 1024; j += 256) {
            float ob = (j < 512) ? p.outb0[j] : p.outb1[j - 512];
            acc += ob * p.fuW[(size_t)j * 512 + n];
        }
        red[tid] = acc;
        __syncthreads();
        for (int s = 128; s > 0; s >>= 1) {
            if (tid < s) red[tid] += red[tid + s];
            __syncthreads();
        }
        if (tid == 0) p.BFof[n] = red[0] + p.fub[n];
    }
}

// ---- mega kernel: in-proj (0..1023) + dt-fold (1024..1535) + out-fold (1536..1791) ----
__global__ __launch_bounds__(256) void mega_k(KP p)
{
    __shared__ ushortT As[2 * 128 * 64];
    __shared__ ushortT Bs[2 * 64 * 64];
    int job = blockIdx.x;
    if (job < 1024) {
        int xc = job & 7;
        int k = job >> 3;
        int dir = xc & 1;
        int q = xc >> 1;
        int bx = q * 8 + (k & 7);
        int by = k >> 3;
        gemm_core<128, 64>(As, Bs, by * 128, bx * 64,
            p.XB, DM, dir, nullptr, 0,
            p.WtIn + (size_t)dir * 2 * DI * DM,
            dir ? p.inb1 : p.inb0,
            nullptr, 0, nullptr, 0, DI,
            p.XSb + (size_t)dir * L_SEQ * DI, DI,
            p.Zb + (size_t)dir * L_SEQ * DI, DI,
            L_SEQ, 2 * DI, DM, 0);
    } else if (job < 1536) {
        int j = job - 1024;
        int d = j >> 8;
        int t = j & 255;
        gemm_core<64, 64>(As, Bs, (t >> 4) * 64, (t & 15) * 64,
            p.WtDt + (size_t)d * DI * DI, DI, 0, nullptr, 0,
            p.XpD + (size_t)d * DI * DI,
            nullptr, nullptr, 0, nullptr, 0, DI,
            p.WtXpF + (size_t)d * NSP * DI, DI, nullptr, 0,
            DI, DI, DI, 0);
    } else {
        int j = job - 1536;
        int d = j >> 7;
        int t = j & 127;
        gemm_core<64, 64>(As, Bs, (t >> 4) * 64, (t & 15) * 64,
            p.WtFu + (size_t)d * DM, DI, 0, nullptr, 0,
            p.OutC + (size_t)d * DI * DM,
            nullptr, nullptr, 0, nullptr, 0, DI,
            p.WtOF2 + (size_t)d * DI, 2 * DI, nullptr, 0,
            DM, DI, DM, 0);
    }
}

// ---- conv kernel ----
__global__ __launch_bounds__(256) void conv_k(KP p)
{
    int job = blockIdx.x;
    int dir = job >> 11;
    int bx = job & 2047;
    const ushortT* XSb = p.XSb + (size_t)dir * L_SEQ * DI;
    ushortT* SCb = p.SCb + (size_t)dir * L_SEQ * DI;
    const float* cw = dir ? p.cw1 : p.cw0;
    const float* cb = dir ? p.cb1 : p.cb0;
    int idx = (bx * 256 + threadIdx.x) * 4;
    int d4 = idx & (DI - 1);
    int l = idx >> 10;
    ushort4_t r0 = *(const ushort4_t*)(XSb + (size_t)l * DI + d4);
    ushort4_t r1 = (l >= 1) ? *(const ushort4_t*)(XSb + (size_t)(l - 1) * DI + d4) : (ushort4_t){0,0,0,0};
    ushort4_t r2 = (l >= 2) ? *(const ushort4_t*)(XSb + (size_t)(l - 2) * DI + d4) : (ushort4_t){0,0,0,0};
    ushort4_t r3 = (l >= 3) ? *(const ushort4_t*)(XSb + (size_t)(l - 3) * DI + d4) : (ushort4_t){0,0,0,0};
    ushort4_t outv;
    #pragma unroll
    for (int j = 0; j < 4; ++j) {
        int d = d4 + j;
        float acc = cb[d] + cw[d * 4 + 0] * b2f(r3[j]) + cw[d * 4 + 1] * b2f(r2[j])
                  + cw[d * 4 + 2] * b2f(r1[j]) + cw[d * 4 + 3] * b2f(r0[j]);
        outv[j] = f2bf(acc * sigm(acc));
    }
    *(ushort4_t*)(SCb + idx) = outv;
}

// ---- xp kernel (544 blocks) ----
__global__ __launch_bounds__(256) void xp_k(KP p)
{
    __shared__ ushortT As[2 * 128 * 64];
    __shared__ ushortT Bs[2 * 64 * 64];
    int job = blockIdx.x;
    int xc = job & 7;
    int k = job >> 3;
    int dir = xc & 1;
    int mq = xc >> 1;
    int bx = k >> 2;
    int by = mq * 4 + (k & 3);
    gemm_core<128, 64>(As, Bs, by * 128, bx * 64,
        p.SCb + (size_t)dir * L_SEQ * DI, DI, 0, nullptr, 0,
        p.WtXpF + (size_t)dir * NSP * DI,
        dir ? p.BFdt1 : p.BFdt0,
        nullptr, 0,
        p.BCf + (size_t)dir * L_SEQ * 32, 32, DI,
        p.DTbB + (size_t)dir * L_SEQ * DI, DI, nullptr, 0,
        L_SEQ, NSP, DI, 1);
}

// ---- single-pass chained scan (decoupled lookback) ----
// job: dir = b>>8, c = (b>>2)&63, dblk = b&3; chain = (dir, dblk)
__global__ __launch_bounds__(256) void scan_k(KP p)
{
    __shared__ float Bsh[CL][DS];
    __shared__ float Csh[CL][DS];
    int job = blockIdx.x;
    int dir = job >> 8;
    int c = (job >> 2) & 63;
    int dblk = job & 3;
    int d = dblk * 256 + threadIdx.x;
    const ushortT* DTb = p.DTbB + (size_t)dir * L_SEQ * DI;
    const ushortT* XSb = p.XSb + (size_t)dir * L_SEQ * DI;
    const float* BC = p.BCf + (size_t)dir * L_SEQ * 32;
    const ushortT* Zb = p.Zb + (size_t)dir * L_SEQ * DI;
    ushortT* Gb = p.Gb + (size_t)dir * L_SEQ * DI;
    const float* cw = dir ? p.cw1 : p.cw0;
    const float* cb = dir ? p.cb1 : p.cb0;
    const int fb = (dir * 4 + dblk) * NC;   // flag base for this chain
    int l0 = c * CL;

    for (int i = threadIdx.x; i < CL * DS; i += 256) {
        int ll = i >> 4, ss = i & 15;
        size_t base = (size_t)(l0 + ll) * 32;
        Bsh[ll][ss] = BC[base + ss];
        Csh[ll][ss] = BC[base + DS + ss];
    }
    __syncthreads();

    float w0 = cw[d * 4 + 0], w1 = cw[d * 4 + 1], w2 = cw[d * 4 + 2], w3 = cw[d * 4 + 3];
    float cbv = cb[d];
    float Ae[DS];
    #pragma unroll
    for (int s = 0; s < DS; ++s) Ae[s] = -__expf(p.Alog[d * DS + s]);

    // ---- phase 1: local scan from h=0; publish (P, h_local) ----
    {
        float x3 = (l0 >= 3) ? b2f(XSb[(size_t)(l0 - 3) * DI + d]) : 0.f;
        float x2 = (l0 >= 2) ? b2f(XSb[(size_t)(l0 - 2) * DI + d]) : 0.f;
        float x1 = (l0 >= 1) ? b2f(XSb[(size_t)(l0 - 1) * DI + d]) : 0.f;
        float h[DS], P[DS];
        #pragma unroll
        for (int s = 0; s < DS; ++s) { h[s] = 0.f; P[s] = 1.f; }
        for (int t = 0; t < CL; ++t) {
            int l = l0 + t;
            float x0 = b2f(XSb[(size_t)l * DI + d]);
            float xv = cbv + w0 * x3 + w1 * x2 + w2 * x1 + w3 * x0;
            x3 = x2; x2 = x1; x1 = x0;
            float dt = b2f(DTb[(size_t)l * DI + d]);
            float dtx = dt * xv;
            #pragma unroll
            for (int s = 0; s < DS; ++s) {
                float e = __expf(dt * Ae[s]);
                h[s] = e * h[s] + dtx * Bsh[t][s];
                P[s] *= e;
            }
        }
        size_t o = ((size_t)(dir * NC + c) * DI + d) * DS;
        #pragma unroll
        for (int s = 0; s < DS; ++s) { p.Pend[o + s] = P[s]; p.Hl[o + s] = h[s]; }
    }
    __syncthreads();
    __threadfence();
    if (threadIdx.x == 0)
        __hip_atomic_store(&p.flags[fb + c], 1, __ATOMIC_RELEASE, __HIP_MEMORY_SCOPE_AGENT);

    // ---- phase 2: lookback combine -> h_start ----
    if (threadIdx.x == 0) {
        for (int j = 0; j < c; ++j)
            while (__hip_atomic_load(&p.flags[fb + j], __ATOMIC_ACQUIRE,
                                     __HIP_MEMORY_SCOPE_AGENT) == 0)
                __builtin_amdgcn_s_sleep(8);
    }
    __syncthreads();
    float h[DS];
    #pragma unroll
    for (int s = 0; s < DS; ++s) h[s] = 0.f;
    for (int j = 0; j < c; ++j) {
        size_t o = ((size_t)(dir * NC + j) * DI + d) * DS;
        #pragma unroll
        for (int s = 0; s < DS; ++s) {
            float P = __hip_atomic_load(&p.Pend[o + s], __ATOMIC_RELAXED, __HIP_MEMORY_SCOPE_AGENT);
            float H = __hip_atomic_load(&p.Hl[o + s],   __ATOMIC_RELAXED, __HIP_MEMORY_SCOPE_AGENT);
            h[s] = P * h[s] + H;
        }
    }

    // ---- phase 3: recompute with true h_start; emit gated outputs ----
    {
        float x3 = (l0 >= 3) ? b2f(XSb[(size_t)(l0 - 3) * DI + d]) : 0.f;
        float x2 = (l0 >= 2) ? b2f(XSb[(size_t)(l0 - 2) * DI + d]) : 0.f;
        float x1 = (l0 >= 1) ? b2f(XSb[(size_t)(l0 - 1) * DI + d]) : 0.f;
        float dpv = p.Dp[d];
        for (int t = 0; t < CL; ++t) {
            int l = l0 + t;
            float x0 = b2f(XSb[(size_t)l * DI + d]);
            float xv = cbv + w0 * x3 + w1 * x2 + w2 * x1 + w3 * x0;
            x3 = x2; x2 = x1; x1 = x0;
            float dt = b2f(DTb[(size_t)l * DI + d]);
            float dtx = dt * xv;
            float y = 0.f;
            #pragma unroll
            for (int s = 0; s < DS; ++s) {
                float e = __expf(dt * Ae[s]);
                h[s] = e * h[s] + dtx * Bsh[t][s];
                y += h[s] * Csh[t][s];
            }
            y += dpv * xv;
            float z = b2f(Zb[(size_t)l * DI + d]);
            Gb[(size_t)l * DI + d] = f2bf(y * (z * sigm(z)));
        }
    }
}

// ---- final fused out-proj + fusion GEMM ----
__global__ __launch_bounds__(256) void final_k(KP p)
{
    __shared__ ushortT As[2 * 64 * 64];
    __shared__ ushortT Bs[2 * 32 * 64];
    int job = blockIdx.x;
    int xc = job & 7;
    int k = job >> 3;
    int by = xc * 4 + (k & 3);
    int bx = k >> 2;
    gemm_core<64, 32>(As, Bs, by * 64, bx * 32,
        p.Gb, DI, 0, p.Gb + (size_t)L_SEQ * DI, 1,
        p.WtOF2, p.BFof,
        p.out, DM, nullptr, 0, DM,
        nullptr, 0, nullptr, 0,
        L_SEQ, DM, 2 * DI, 0);
}

extern "C" void kernel_launch(void* const* d_in, const int* in_sizes, int n_in,
                              void* d_out, int out_size, void* d_ws, size_t ws_size,
                              hipStream_t stream)
{
    (void)in_sizes; (void)n_in; (void)out_size; (void)ws_size;
    const float* x = (const float*)d_in[0];
    const float* inW[2]  = {(const float*)d_in[1],  (const float*)d_in[11]};
    const float* inb[2]  = {(const float*)d_in[2],  (const float*)d_in[12]};
    const float* cw[2]   = {(const float*)d_in[3],  (const float*)d_in[13]};
    const float* cb[2]   = {(const float*)d_in[4],  (const float*)d_in[14]};
    const float* xpW[2]  = {(const float*)d_in[5],  (const float*)d_in[15]};
    const float* xpb[2]  = {(const float*)d_in[6],  (const float*)d_in[16]};
    const float* dtW[2]  = {(const float*)d_in[7],  (const float*)d_in[17]};
    const float* dtb[2]  = {(const float*)d_in[8],  (const float*)d_in[18]};
    const float* outW[2] = {(const float*)d_in[9],  (const float*)d_in[19]};
    const float* outb[2] = {(const float*)d_in[10], (const float*)d_in[20]};
    const float* Alog = (const float*)d_in[21];
    const float* Dp   = (const float*)d_in[22];
    const float* fuW  = (const float*)d_in[23];
    const float* fub  = (const float*)d_in[24];
    float* out = (float*)d_out;

    float* ws = (float*)d_ws;
    size_t off = 0;
    auto alloc = [&](size_t n) { float* p = ws + off; off += n; return p; };
    float* BCf  = alloc((size_t)2 * L_SEQ * 32);
    float* Pend = alloc((size_t)2 * NC * DI * DS);
    float* Hl   = alloc((size_t)2 * NC * DI * DS);
    float* BFdt0 = alloc(1056);
    float* BFdt1 = alloc(1056);
    float* BFof  = alloc(512);
    int*   flags = (int*)alloc(512);

    ushortT* wsu = (ushortT*)(ws + off);
    size_t uoff = 0;
    auto ualloc = [&](size_t n) { ushortT* p = wsu + uoff; uoff += n; return p; };
    ushortT* WtIn  = ualloc((size_t)2 * (2 * DI) * DM);
    ushortT* WtDt  = ualloc((size_t)2 * DI * DI);
    ushortT* WtFu  = ualloc((size_t)DM * DI);
    ushortT* WtXpF = ualloc((size_t)2 * NSP * DI);
    ushortT* XpD   = ualloc((size_t)2 * DI * DI);
    ushortT* OutC  = ualloc((size_t)2 * DI * DM);
    ushortT* WtOF2 = ualloc((size_t)DM * 2 * DI);
    ushortT* XB    = ualloc((size_t)L_SEQ * DM);
    ushortT* XSb   = ualloc((size_t)2 * L_SEQ * DI);
    ushortT* Zb    = ualloc((size_t)2 * L_SEQ * DI);
    ushortT* SCb   = ualloc((size_t)2 * L_SEQ * DI);
    ushortT* DTbB  = ualloc((size_t)2 * L_SEQ * DI);
    ushortT* Gb    = ualloc((size_t)2 * L_SEQ * DI);

    KP p;
    struct E { const float* s; ushortT* d; int ss, so, ds, N, K, mode; };
    E es[11] = {
        {inW[0],  WtIn,                          2 * DI, 0,    DM, 2 * DI, DM, 0},
        {inW[1],  WtIn + (size_t)2 * DI * DM,    2 * DI, 0,    DM, 2 * DI, DM, 0},
        {dtW[0],  WtDt,                          DI,     0,    DI, DI,     DI, 0},
        {dtW[1],  WtDt + (size_t)DI * DI,        DI,     0,    DI, DI,     DI, 0},
        {fuW,     WtFu,                          DM,     0,    DI, DM,     DI, 0},
        {xpW[0],  WtXpF + (size_t)DI * DI,       NSP,    DI,   DI, 32,     DI, 0},
        {xpW[1],  WtXpF + (size_t)NSP * DI + (size_t)DI * DI, NSP, DI, DI, 32, DI, 0},
        {xpW[0],  XpD,                           NSP,    0,    DI, DI,     DI, 1},
        {xpW[1],  XpD + (size_t)DI * DI,         NSP,    0,    DI, DI,     DI, 1},
        {outW[0], OutC,                          DM,     0,    DM, DM,     DI, 1},
        {outW[1], OutC + (size_t)DI * DM,        DM,     0,    DM, DM,     DI, 1},
    };
    p.wc.off[0] = 0;
    for (int m = 0; m < 11; ++m) {
        p.wc.src[m] = es[m].s; p.wc.dst[m] = es[m].d;
        p.wc.ss[m] = es[m].ss; p.wc.soff[m] = es[m].so; p.wc.ds_[m] = es[m].ds;
        p.wc.tN[m] = es[m].N / 32; p.wc.mode[m] = es[m].mode;
        p.wc.off[m + 1] = p.wc.off[m] + (es[m].N / 32) * (es[m].K / 32);
    }
    p.nW = p.wc.off[11];
    p.nprep = p.nW + 1024 + 2624;
    p.x = x; p.XB = XB;
    p.xpb0 = xpb[0]; p.xpb1 = xpb[1];
    p.dtW0 = dtW[0]; p.dtW1 = dtW[1];
    p.dtb0 = dtb[0]; p.dtb1 = dtb[1];
    p.outb0 = outb[0]; p.outb1 = outb[1];
    p.fuW = fuW; p.fub = fub;
    p.BFdt0 = BFdt0; p.BFdt1 = BFdt1; p.BFof = BFof;
    p.inb0 = inb[0]; p.inb1 = inb[1];
    p.WtIn = WtIn; p.WtDt = WtDt; p.WtFu = WtFu; p.WtXpF = WtXpF;
    p.XpD = XpD; p.OutC = OutC; p.WtOF2 = WtOF2;
    p.XSb = XSb; p.Zb = Zb; p.SCb = SCb; p.DTbB = DTbB; p.Gb = Gb;
    p.BCf = BCf;
    p.cw0 = cw[0]; p.cw1 = cw[1]; p.cb0 = cb[0]; p.cb1 = cb[1];
    p.Alog = Alog; p.Dp = Dp;
    p.Pend = Pend; p.Hl = Hl;
    p.flags = flags;
    p.out = out;

    dim3 blk(256);
    hipMemsetAsync(flags, 0, 512 * sizeof(int), stream);
    prep_k <<<dim3(p.nprep), blk, 0, stream>>>(p);
    mega_k <<<dim3(1792),    blk, 0, stream>>>(p);
    conv_k <<<dim3(4096),    blk, 0, stream>>>(p);
    xp_k   <<<dim3(544),     blk, 0, stream>>>(p);
    scan_k <<<dim3(512),     blk, 0, stream>>>(p);
    final_k<<<dim3(512),     blk, 0, stream>>>(p);
}

// Round 14
// 338.984 us; speedup vs baseline: 2.8105x; 2.8105x over previous
//
#include <hip/hip_runtime.h>
#include <cmath>

#define L_SEQ 2048
#define DM 512
#define DI 1024      // D_INNER
#define DS 16        // D_STATE
#define NSP 1056     // DI + 2*DS
#define NC 64        // scan chunks
#define CL 32        // chunk length

typedef unsigned short ushortT;
typedef unsigned int u32;
typedef __attribute__((ext_vector_type(8))) short short8;
typedef __attribute__((ext_vector_type(4))) unsigned short ushort4_t;
typedef __attribute__((ext_vector_type(4))) float float4_t;
typedef __attribute__((address_space(1))) u32 gu32;
typedef __attribute__((address_space(3))) u32 lu32;

__device__ __forceinline__ float sigm(float x) { return 1.0f / (1.0f + __expf(-x)); }

__device__ __forceinline__ ushortT f2bf(float f) {
    unsigned u = __float_as_uint(f);
    unsigned r = u + 0x7FFFu + ((u >> 16) & 1u);
    return (ushortT)(r >> 16);
}
__device__ __forceinline__ float b2f(ushortT u) {
    return __uint_as_float(((u32)u) << 16);
}
__device__ __forceinline__ void gl2lds16(const ushortT* g, ushortT* l) {
    __builtin_amdgcn_global_load_lds((gu32*)g, (lu32*)l, 16, 0, 0);
}

struct WC {
    const float* src[11];
    ushortT* dst[11];
    int ss[11], soff[11], ds_[11], tN[11], mode[11];
    int off[12];
};

struct KP {
    WC wc; int nW, nprep;
    const float* x; ushortT* XB;
    const float *xpb0, *xpb1, *dtW0, *dtW1, *dtb0, *dtb1;
    const float *outb0, *outb1, *fuW, *fub;
    float *BFdt0, *BFdt1, *BFof;
    const float *inb0, *inb1;
    ushortT *WtIn, *WtDt, *WtFu, *WtXpF, *XpD, *OutC, *WtOF2;
    ushortT *XSb, *Zb, *SCb, *DTbB, *Gb;
    float *BCf;
    const float *cw0, *cw1, *cb0, *cb1;
    const float *Alog, *Dp;
    float *Pend, *Hl, *Hs;
    float* out;
};

// ---- MFMA GEMM tile (BK=64, double-buffered LDS, XOR bank swizzle) ----
// epi: 0 none, 1 softplus on cols<Nsplit, 3 atomicAdd into Cf
template<int BM, int BN>
__device__ void gemm_core(
    ushortT* As, ushortT* Bs, int bm, int bn,
    const ushortT* __restrict__ A, int lda, int revA,
    const ushortT* __restrict__ W, int ldw,
    const float* __restrict__ bias,
    float* __restrict__ Cf, int ldcf,
    float* __restrict__ Cf2, int ldcf2, int Nsplit,
    ushortT* __restrict__ Cb, int ldcb,
    ushortT* __restrict__ Cb2, int ldcb2,
    int M, int N, int K, int epi)
{
    constexpr int BK = 64;
    constexpr int MI = BM / 32;
    constexpr int NI = BN / 32;
    constexpr int CA = BM / 32;
    constexpr int CB = BN / 32;
    constexpr int ABUF = BM * BK;
    constexpr int BBUF = BN * BK;

    const int tid  = threadIdx.x;
    const int wave = tid >> 6;
    const int lane = tid & 63;
    const int quad = lane >> 4;
    const int r    = lane & 15;
    const int wm   = (wave >> 1) * (BM / 2);
    const int wn   = (wave & 1) * (BN / 2);

    const int lrow = lane >> 3;
    const int lk   = ((lane & 7) ^ lrow) * 8;

    const ushortT* gA[CA]; ushortT* lA[CA];
    #pragma unroll
    for (int c = 0; c < CA; ++c) {
        int row = bm + c * 32 + wave * 8 + lrow;
        int r0 = revA ? (M - 1 - row) : row;
        gA[c] = A + (size_t)r0 * lda + lk;
        lA[c] = &As[(c * 32 + wave * 8) * BK];
    }
    const ushortT* gB[CB]; ushortT* lB[CB];
    #pragma unroll
    for (int c = 0; c < CB; ++c) {
        int row = bn + c * 32 + wave * 8 + lrow;
        if (row > N - 1) row = N - 1;
        gB[c] = W + (size_t)row * ldw + lk;
        lB[c] = &Bs[(c * 32 + wave * 8) * BK];
    }

    float4_t acc[MI][NI];
    #pragma unroll
    for (int i = 0; i < MI; ++i)
        #pragma unroll
        for (int j = 0; j < NI; ++j)
            acc[i][j] = (float4_t){0.f, 0.f, 0.f, 0.f};

    const int nsteps = K >> 6;

    auto stage = [&](int step, int buf) {
        int kq = step << 6;
        #pragma unroll
        for (int c = 0; c < CA; ++c) gl2lds16(gA[c] + kq, lA[c] + buf * ABUF);
        #pragma unroll
        for (int c = 0; c < CB; ++c) gl2lds16(gB[c] + kq, lB[c] + buf * BBUF);
    };
    auto compute = [&](int buf) {
        #pragma unroll
        for (int kh = 0; kh < 2; ++kh) {
            const int slot = (((kh * 4 + quad) ^ (lane & 7)) * 8);
            short8 af[MI], bf[NI];
            #pragma unroll
            for (int mi = 0; mi < MI; ++mi)
                af[mi] = *(const short8*)&As[buf * ABUF + (wm + mi * 16 + r) * BK + slot];
            #pragma unroll
            for (int ni = 0; ni < NI; ++ni)
                bf[ni] = *(const short8*)&Bs[buf * BBUF + (wn + ni * 16 + r) * BK + slot];
            #pragma unroll
            for (int mi = 0; mi < MI; ++mi)
                #pragma unroll
                for (int ni = 0; ni < NI; ++ni)
                    acc[mi][ni] = __builtin_amdgcn_mfma_f32_16x16x32_bf16(
                        af[mi], bf[ni], acc[mi][ni], 0, 0, 0);
        }
    };

    stage(0, 0);
    for (int i = 0; i < nsteps; i += 2) {
        __syncthreads();
        if (i + 1 < nsteps) stage(i + 1, 1);
        compute(0);
        __syncthreads();
        if (i + 2 < nsteps) stage(i + 2, 0);
        compute(1);
    }

    // epilogue: C/D layout col = lane&15, row = quad*4 + reg
    #pragma unroll
    for (int mi = 0; mi < MI; ++mi) {
        int rowb = bm + wm + mi * 16 + quad * 4;
        #pragma unroll
        for (int ni = 0; ni < NI; ++ni) {
            int gn = bn + wn + ni * 16 + r;
            if (gn < N) {
                float bv = bias ? bias[gn] : 0.0f;
                #pragma unroll
                for (int j = 0; j < 4; ++j) {
                    int orow = rowb + j;
                    float v = acc[mi][ni][j] + bv;
                    if (epi == 3) {
                        atomicAdd(&Cf[(size_t)orow * ldcf + gn], v);
                    } else if (gn < Nsplit) {
                        if (epi == 1) v = (v > 20.0f) ? v : log1pf(__expf(v));
                        if (Cf) Cf[(size_t)orow * ldcf + gn] = v;
                        if (Cb) Cb[(size_t)orow * ldcb + gn] = f2bf(v);
                    } else {
                        if (Cf2) Cf2[(size_t)orow * ldcf2 + gn - Nsplit] = v;
                        if (Cb2) Cb2[(size_t)orow * ldcb2 + gn - Nsplit] = f2bf(v);
                    }
                }
            }
        }
    }
}

// ---- prep kernel: weight cvt / x cvt / bias folds ----
__global__ __launch_bounds__(256) void prep_k(KP p)
{
    __shared__ ushortT smem[2624];
    ushortT (*t)[33] = (ushortT(*)[33])smem;
    float* red = (float*)(smem + 2112);
    int b = blockIdx.x;
    int tid = threadIdx.x;
    if (b < p.nW) {
        const WC& wc = p.wc;
        int m = 0;
        while (b >= wc.off[m + 1]) ++m;
        int tl = b - wc.off[m];
        int n0 = (tl % wc.tN[m]) * 32;
        int k0 = (tl / wc.tN[m]) * 32;
        const float* W = wc.src[m];
        ushortT* D = wc.dst[m];
        int ss = wc.ss[m], soff = wc.soff[m], ds = wc.ds_[m];
        int tx = tid & 31, ty = tid >> 5;
        if (wc.mode[m] == 1) {
            #pragma unroll
            for (int i = 0; i < 32; i += 8)
                D[(size_t)(k0 + ty + i) * ds + n0 + tx] =
                    f2bf(W[(size_t)(k0 + ty + i) * ss + soff + n0 + tx]);
        } else {
            #pragma unroll
            for (int i = 0; i < 32; i += 8)
                t[ty + i][tx] = f2bf(W[(size_t)(k0 + ty + i) * ss + soff + n0 + tx]);
            __syncthreads();
            #pragma unroll
            for (int i = 0; i < 32; i += 8)
                D[(size_t)(n0 + ty + i) * ds + k0 + tx] = t[tx][ty + i];
        }
        return;
    }
    b -= p.nW;
    if (b < 1024) {
        int i = (b * 256 + tid) * 4;
        float4_t v = *(const float4_t*)(p.x + i);
        p.XB[i + 0] = f2bf(v[0]); p.XB[i + 1] = f2bf(v[1]);
        p.XB[i + 2] = f2bf(v[2]); p.XB[i + 3] = f2bf(v[3]);
        return;
    }
    int o = b - 1024;
    float acc = 0.0f;
    if (o < 2112) {
        int dir = o >= 1056;
        int m = o - dir * 1056;
        const float* xpb = dir ? p.xpb1 : p.xpb0;
        float* BF = dir ? p.BFdt1 : p.BFdt0;
        if (m >= 1024) {
            if (tid == 0) BF[m] = xpb[m];
            return;
        }
        const float* dtW = dir ? p.dtW1 : p.dtW0;
        const float* dtb = dir ? p.dtb1 : p.dtb0;
        for (int n = tid; n < 1024; n += 256) acc += xpb[n] * dtW[n * 1024 + m];
        red[tid] = acc;
        __syncthreads();
        for (int s = 128; s > 0; s >>= 1) {
            if (tid < s) red[tid] += red[tid + s];
            __syncthreads();
        }
        if (tid == 0) BF[m] = red[0] + dtb[m];
    } else {
        int n = o - 2112;
        for (int j = tid; j < 1024; j += 256) {
            float ob = (j < 512) ? p.outb0[j] : p.outb1[j - 512];
            acc += ob * p.fuW[(size_t)j * 512 + n];
        }
        red[tid] = acc;
        __syncthreads();
        for (int s = 128; s > 0; s >>= 1) {
            if (tid < s) red[tid] += red[tid + s];
            __syncthreads();
        }
        if (tid == 0) p.BFof[n] = red[0] + p.fub[n];
    }
}

// ---- mega kernel: in-proj (0..1023) + dt-fold (1024..1535) + out-fold (1536..1791) ----
__global__ __launch_bounds__(256) void mega_k(KP p)
{
    __shared__ ushortT As[2 * 128 * 64];
    __shared__ ushortT Bs[2 * 64 * 64];
    int job = blockIdx.x;
    if (job < 1024) {
        int xc = job & 7;
        int k = job >> 3;
        int dir = xc & 1;
        int q = xc >> 1;
        int bx = q * 8 + (k & 7);
        int by = k >> 3;
        gemm_core<128, 64>(As, Bs, by * 128, bx * 64,
            p.XB, DM, dir,
            p.WtIn + (size_t)dir * 2 * DI * DM, DM,
            dir ? p.inb1 : p.inb0,
            nullptr, 0, nullptr, 0, DI,
            p.XSb + (size_t)dir * L_SEQ * DI, DI,
            p.Zb + (size_t)dir * L_SEQ * DI, DI,
            L_SEQ, 2 * DI, DM, 0);
    } else if (job < 1536) {
        int j = job - 1024;
        int d = j >> 8;
        int t = j & 255;
        gemm_core<64, 64>(As, Bs, (t >> 4) * 64, (t & 15) * 64,
            p.WtDt + (size_t)d * DI * DI, DI, 0,
            p.XpD + (size_t)d * DI * DI, DI,
            nullptr, nullptr, 0, nullptr, 0, DI,
            p.WtXpF + (size_t)d * NSP * DI, DI, nullptr, 0,
            DI, DI, DI, 0);
    } else {
        int j = job - 1536;
        int d = j >> 7;
        int t = j & 127;
        gemm_core<64, 64>(As, Bs, (t >> 4) * 64, (t & 15) * 64,
            p.WtFu + (size_t)d * DM, DI, 0,
            p.OutC + (size_t)d * DI * DM, DM,
            nullptr, nullptr, 0, nullptr, 0, DI,
            p.WtOF2 + (size_t)d * DI, 2 * DI, nullptr, 0,
            DM, DI, DM, 0);
    }
}

// ---- conv kernel ----
__global__ __launch_bounds__(256) void conv_k(KP p)
{
    int job = blockIdx.x;
    int dir = job >> 11;
    int bx = job & 2047;
    const ushortT* XSb = p.XSb + (size_t)dir * L_SEQ * DI;
    ushortT* SCb = p.SCb + (size_t)dir * L_SEQ * DI;
    const float* cw = dir ? p.cw1 : p.cw0;
    const float* cb = dir ? p.cb1 : p.cb0;
    int idx = (bx * 256 + threadIdx.x) * 4;
    int d4 = idx & (DI - 1);
    int l = idx >> 10;
    ushort4_t r0 = *(const ushort4_t*)(XSb + (size_t)l * DI + d4);
    ushort4_t r1 = (l >= 1) ? *(const ushort4_t*)(XSb + (size_t)(l - 1) * DI + d4) : (ushort4_t){0,0,0,0};
    ushort4_t r2 = (l >= 2) ? *(const ushort4_t*)(XSb + (size_t)(l - 2) * DI + d4) : (ushort4_t){0,0,0,0};
    ushort4_t r3 = (l >= 3) ? *(const ushort4_t*)(XSb + (size_t)(l - 3) * DI + d4) : (ushort4_t){0,0,0,0};
    ushort4_t outv;
    #pragma unroll
    for (int j = 0; j < 4; ++j) {
        int d = d4 + j;
        float acc = cb[d] + cw[d * 4 + 0] * b2f(r3[j]) + cw[d * 4 + 1] * b2f(r2[j])
                  + cw[d * 4 + 2] * b2f(r1[j]) + cw[d * 4 + 3] * b2f(r0[j]);
        outv[j] = f2bf(acc * sigm(acc));
    }
    *(ushort4_t*)(SCb + idx) = outv;
}

// ---- xp kernel (544 blocks) ----
__global__ __launch_bounds__(256) void xp_k(KP p)
{
    __shared__ ushortT As[2 * 128 * 64];
    __shared__ ushortT Bs[2 * 64 * 64];
    int job = blockIdx.x;
    int xc = job & 7;
    int k = job >> 3;
    int dir = xc & 1;
    int mq = xc >> 1;
    int bx = k >> 2;
    int by = mq * 4 + (k & 3);
    gemm_core<128, 64>(As, Bs, by * 128, bx * 64,
        p.SCb + (size_t)dir * L_SEQ * DI, DI, 0,
        p.WtXpF + (size_t)dir * NSP * DI, DI,
        dir ? p.BFdt1 : p.BFdt0,
        nullptr, 0,
        p.BCf + (size_t)dir * L_SEQ * 32, 32, DI,
        p.DTbB + (size_t)dir * L_SEQ * DI, DI, nullptr, 0,
        L_SEQ, NSP, DI, 1);
}

// ---- scanA: local scan per (dir, chunk, d-block) with rolling conv ----
__global__ __launch_bounds__(256) void scanA_k(KP p)
{
    __shared__ float Bsh[CL][DS];
    int job = blockIdx.x;
    int dir = job >> 8;
    int c = (job & 255) >> 2;
    int d = (job & 3) * 256 + threadIdx.x;
    const ushortT* DTb = p.DTbB + (size_t)dir * L_SEQ * DI;
    const ushortT* XSb = p.XSb + (size_t)dir * L_SEQ * DI;
    const float* BC = p.BCf + (size_t)dir * L_SEQ * 32;
    const float* cw = dir ? p.cw1 : p.cw0;
    const float* cb = dir ? p.cb1 : p.cb0;
    int l0 = c * CL;
    for (int i = threadIdx.x; i < CL * DS; i += 256) {
        int ll = i >> 4, ss = i & 15;
        Bsh[ll][ss] = BC[(size_t)(l0 + ll) * 32 + ss];
    }
    __syncthreads();
    float w0 = cw[d * 4 + 0], w1 = cw[d * 4 + 1], w2 = cw[d * 4 + 2], w3 = cw[d * 4 + 3];
    float cbv = cb[d];
    float x3 = (l0 >= 3) ? b2f(XSb[(size_t)(l0 - 3) * DI + d]) : 0.f;
    float x2 = (l0 >= 2) ? b2f(XSb[(size_t)(l0 - 2) * DI + d]) : 0.f;
    float x1 = (l0 >= 1) ? b2f(XSb[(size_t)(l0 - 1) * DI + d]) : 0.f;
    float Ae[DS], h[DS], P[DS];
    #pragma unroll
    for (int s = 0; s < DS; ++s) { Ae[s] = -__expf(p.Alog[d * DS + s]); h[s] = 0.f; P[s] = 1.f; }
    for (int t = 0; t < CL; ++t) {
        int l = l0 + t;
        float x0 = b2f(XSb[(size_t)l * DI + d]);
        float xv = cbv + w0 * x3 + w1 * x2 + w2 * x1 + w3 * x0;
        x3 = x2; x2 = x1; x1 = x0;
        float dt = b2f(DTb[(size_t)l * DI + d]);
        float dtx = dt * xv;
        #pragma unroll
        for (int s = 0; s < DS; ++s) {
            float e = __expf(dt * Ae[s]);
            h[s] = e * h[s] + dtx * Bsh[t][s];
            P[s] *= e;
        }
    }
    size_t o = ((size_t)(dir * NC + c) * DI + d) * DS;
    #pragma unroll
    for (int s = 0; s < DS; ++s) { p.Pend[o + s] = P[s]; p.Hl[o + s] = h[s]; }
}

// ---- scanB: combine chunk summaries ----
__global__ __launch_bounds__(256) void scanB_k(KP p)
{
    int idx = blockIdx.x * 256 + threadIdx.x;
    float h = 0.f;
    int ds = idx & 16383;
    int dir = idx >> 14;
    for (int c = 0; c < NC; ++c) {
        size_t o = ((size_t)(dir * NC + c)) * (DI * DS) + ds;
        p.Hs[o] = h;
        h = p.Pend[o] * h + p.Hl[o];
    }
}

// ---- scanC: recompute with true h_start; emit gated outputs ----
__global__ __launch_bounds__(256) void scanC_k(KP p)
{
    __shared__ float Bsh[CL][DS];
    __shared__ float Csh[CL][DS];
    int job = blockIdx.x;
    int dir = job >> 8;
    int c = (job & 255) >> 2;
    int d = (job & 3) * 256 + threadIdx.x;
    const ushortT* DTb = p.DTbB + (size_t)dir * L_SEQ * DI;
    const ushortT* XSb = p.XSb + (size_t)dir * L_SEQ * DI;
    const float* BC = p.BCf + (size_t)dir * L_SEQ * 32;
    const ushortT* Zb = p.Zb + (size_t)dir * L_SEQ * DI;
    ushortT* Gb = p.Gb + (size_t)dir * L_SEQ * DI;
    const float* cw = dir ? p.cw1 : p.cw0;
    const float* cb = dir ? p.cb1 : p.cb0;
    int l0 = c * CL;
    for (int i = threadIdx.x; i < CL * DS; i += 256) {
        int ll = i >> 4, ss = i & 15;
        size_t base = (size_t)(l0 + ll) * 32;
        Bsh[ll][ss] = BC[base + ss];
        Csh[ll][ss] = BC[base + DS + ss];
    }
    __syncthreads();
    float w0 = cw[d * 4 + 0], w1 = cw[d * 4 + 1], w2 = cw[d * 4 + 2], w3 = cw[d * 4 + 3];
    float cbv = cb[d];
    float x3 = (l0 >= 3) ? b2f(XSb[(size_t)(l0 - 3) * DI + d]) : 0.f;
    float x2 = (l0 >= 2) ? b2f(XSb[(size_t)(l0 - 2) * DI + d]) : 0.f;
    float x1 = (l0 >= 1) ? b2f(XSb[(size_t)(l0 - 1) * DI + d]) : 0.f;
    float Ae[DS], h[DS];
    size_t o = ((size_t)(dir * NC + c) * DI + d) * DS;
    #pragma unroll
    for (int s = 0; s < DS; ++s) { Ae[s] = -__expf(p.Alog[d * DS + s]); h[s] = p.Hs[o + s]; }
    float dpv = p.Dp[d];
    for (int t = 0; t < CL; ++t) {
        int l = l0 + t;
        float x0 = b2f(XSb[(size_t)l * DI + d]);
        float xv = cbv + w0 * x3 + w1 * x2 + w2 * x1 + w3 * x0;
        x3 = x2; x2 = x1; x1 = x0;
        float dt = b2f(DTb[(size_t)l * DI + d]);
        float dtx = dt * xv;
        float y = 0.f;
        #pragma unroll
        for (int s = 0; s < DS; ++s) {
            float e = __expf(dt * Ae[s]);
            h[s] = e * h[s] + dtx * Bsh[t][s];
            y += h[s] * Csh[t][s];
        }
        y += dpv * xv;
        float z = b2f(Zb[(size_t)l * DI + d]);
        Gb[(size_t)l * DI + d] = f2bf(y * (z * sigm(z)));
    }
}

// ---- final fused out-proj + fusion GEMM, split by dir (atomicAdd, K=1024) ----
__global__ __launch_bounds__(256) void final_k(KP p)
{
    __shared__ ushortT As[2 * 64 * 64];
    __shared__ ushortT Bs[2 * 32 * 64];
    int job = blockIdx.x;
    int dir = job & 1;            // interleave dirs across XCDs
    int t = job >> 1;             // 0..511
    int xc = t & 7;
    int k = t >> 3;               // 0..63
    int by = xc * 4 + (k & 3);
    int bx = k >> 2;              // 0..15
    gemm_core<64, 32>(As, Bs, by * 64, bx * 32,
        p.Gb + (size_t)dir * L_SEQ * DI, DI, dir,   // dir1 rows reversed
        p.WtOF2 + (size_t)dir * DI, 2 * DI,
        dir ? nullptr : p.BFof,                     // bias added once (dir0)
        p.out, DM, nullptr, 0, DM,
        nullptr, 0, nullptr, 0,
        L_SEQ, DM, DI, 3);
}

extern "C" void kernel_launch(void* const* d_in, const int* in_sizes, int n_in,
                              void* d_out, int out_size, void* d_ws, size_t ws_size,
                              hipStream_t stream)
{
    (void)in_sizes; (void)n_in; (void)out_size; (void)ws_size;
    const float* x = (const float*)d_in[0];
    const float* inW[2]  = {(const float*)d_in[1],  (const float*)d_in[11]};
    const float* inb[2]  = {(const float*)d_in[2],  (const float*)d_in[12]};
    const float* cw[2]   = {(const float*)d_in[3],  (const float*)d_in[13]};
    const float* cb[2]   = {(const float*)d_in[4],  (const float*)d_in[14]};
    const float* xpW[2]  = {(const float*)d_in[5],  (const float*)d_in[15]};
    const float* xpb[2]  = {(const float*)d_in[6],  (const float*)d_in[16]};
    const float* dtW[2]  = {(const float*)d_in[7],  (const float*)d_in[17]};
    const float* dtb[2]  = {(const float*)d_in[8],  (const float*)d_in[18]};
    const float* outW[2] = {(const float*)d_in[9],  (const float*)d_in[19]};
    const float* outb[2] = {(const float*)d_in[10], (const float*)d_in[20]};
    const float* Alog = (const float*)d_in[21];
    const float* Dp   = (const float*)d_in[22];
    const float* fuW  = (const float*)d_in[23];
    const float* fub  = (const float*)d_in[24];
    float* out = (float*)d_out;

    float* ws = (float*)d_ws;
    size_t off = 0;
    auto alloc = [&](size_t n) { float* p = ws + off; off += n; return p; };
    float* BCf  = alloc((size_t)2 * L_SEQ * 32);
    float* Pend = alloc((size_t)2 * NC * DI * DS);
    float* Hl   = alloc((size_t)2 * NC * DI * DS);
    float* Hs   = alloc((size_t)2 * NC * DI * DS);
    float* BFdt0 = alloc(1056);
    float* BFdt1 = alloc(1056);
    float* BFof  = alloc(512);

    ushortT* wsu = (ushortT*)(ws + off);
    size_t uoff = 0;
    auto ualloc = [&](size_t n) { ushortT* p = wsu + uoff; uoff += n; return p; };
    ushortT* WtIn  = ualloc((size_t)2 * (2 * DI) * DM);
    ushortT* WtDt  = ualloc((size_t)2 * DI * DI);
    ushortT* WtFu  = ualloc((size_t)DM * DI);
    ushortT* WtXpF = ualloc((size_t)2 * NSP * DI);
    ushortT* XpD   = ualloc((size_t)2 * DI * DI);
    ushortT* OutC  = ualloc((size_t)2 * DI * DM);
    ushortT* WtOF2 = ualloc((size_t)DM * 2 * DI);
    ushortT* XB    = ualloc((size_t)L_SEQ * DM);
    ushortT* XSb   = ualloc((size_t)2 * L_SEQ * DI);
    ushortT* Zb    = ualloc((size_t)2 * L_SEQ * DI);
    ushortT* SCb   = ualloc((size_t)2 * L_SEQ * DI);
    ushortT* DTbB  = ualloc((size_t)2 * L_SEQ * DI);
    ushortT* Gb    = ualloc((size_t)2 * L_SEQ * DI);

    KP p;
    struct E { const float* s; ushortT* d; int ss, so, ds, N, K, mode; };
    E es[11] = {
        {inW[0],  WtIn,                          2 * DI, 0,    DM, 2 * DI, DM, 0},
        {inW[1],  WtIn + (size_t)2 * DI * DM,    2 * DI, 0,    DM, 2 * DI, DM, 0},
        {dtW[0],  WtDt,                          DI,     0,    DI, DI,     DI, 0},
        {dtW[1],  WtDt + (size_t)DI * DI,        DI,     0,    DI, DI,     DI, 0},
        {fuW,     WtFu,                          DM,     0,    DI, DM,     DI, 0},
        {xpW[0],  WtXpF + (size_t)DI * DI,       NSP,    DI,   DI, 32,     DI, 0},
        {xpW[1],  WtXpF + (size_t)NSP * DI + (size_t)DI * DI, NSP, DI, DI, 32, DI, 0},
        {xpW[0],  XpD,                           NSP,    0,    DI, DI,     DI, 1},
        {xpW[1],  XpD + (size_t)DI * DI,         NSP,    0,    DI, DI,     DI, 1},
        {outW[0], OutC,                          DM,     0,    DM, DM,     DI, 1},
        {outW[1], OutC + (size_t)DI * DM,        DM,     0,    DM, DM,     DI, 1},
    };
    p.wc.off[0] = 0;
    for (int m = 0; m < 11; ++m) {
        p.wc.src[m] = es[m].s; p.wc.dst[m] = es[m].d;
        p.wc.ss[m] = es[m].ss; p.wc.soff[m] = es[m].so; p.wc.ds_[m] = es[m].ds;
        p.wc.tN[m] = es[m].N / 32; p.wc.mode[m] = es[m].mode;
        p.wc.off[m + 1] = p.wc.off[m] + (es[m].N / 32) * (es[m].K / 32);
    }
    p.nW = p.wc.off[11];
    p.nprep = p.nW + 1024 + 2624;
    p.x = x; p.XB = XB;
    p.xpb0 = xpb[0]; p.xpb1 = xpb[1];
    p.dtW0 = dtW[0]; p.dtW1 = dtW[1];
    p.dtb0 = dtb[0]; p.dtb1 = dtb[1];
    p.outb0 = outb[0]; p.outb1 = outb[1];
    p.fuW = fuW; p.fub = fub;
    p.BFdt0 = BFdt0; p.BFdt1 = BFdt1; p.BFof = BFof;
    p.inb0 = inb[0]; p.inb1 = inb[1];
    p.WtIn = WtIn; p.WtDt = WtDt; p.WtFu = WtFu; p.WtXpF = WtXpF;
    p.XpD = XpD; p.OutC = OutC; p.WtOF2 = WtOF2;
    p.XSb = XSb; p.Zb = Zb; p.SCb = SCb; p.DTbB = DTbB; p.Gb = Gb;
    p.BCf = BCf;
    p.cw0 = cw[0]; p.cw1 = cw[1]; p.cb0 = cb[0]; p.cb1 = cb[1];
    p.Alog = Alog; p.Dp = Dp;
    p.Pend = Pend; p.Hl = Hl; p.Hs = Hs;
    p.out = out;

    dim3 blk(256);
    hipMemsetAsync(out, 0, (size_t)L_SEQ * DM * sizeof(float), stream);
    prep_k <<<dim3(p.nprep), blk, 0, stream>>>(p);
    mega_k <<<dim3(1792),    blk, 0, stream>>>(p);
    conv_k <<<dim3(4096),    blk, 0, stream>>>(p);
    xp_k   <<<dim3(544),     blk, 0, stream>>>(p);
    scanA_k<<<dim3(512),     blk, 0, stream>>>(p);
    scanB_k<<<dim3(128),     blk, 0, stream>>>(p);
    scanC_k<<<dim3(512),     blk, 0, stream>>>(p);
    final_k<<<dim3(1024),    blk, 0, stream>>>(p);
}